// Round 1
// 309.444 us; speedup vs baseline: 1.0521x; 1.0521x over previous
//
#include <hip/hip_runtime.h>
#include <hip/hip_fp16.h>

#define N_NODES 50000
#define N_EDGES 800000
#define DIM 128
#define LAYERS 4
#define SLOT 48           // padded slots per node; 4B/slot -> node region = 192B = 3 lines
#define EPB 8             // edges scanned per thread in bucket

typedef __attribute__((ext_vector_type(8))) _Float16 half8;
typedef __attribute__((ext_vector_type(4))) float float4v;
typedef __attribute__((ext_vector_type(4))) int intv4;
typedef __attribute__((ext_vector_type(4))) float fltv4;

// pack: src (u16) | w (fp16) << 16
__device__ __forceinline__ int pack_edge(int s, float w) {
    return (int)(((unsigned)__half_as_ushort(__float2half(w)) << 16) | (unsigned)(s & 0xFFFF));
}

// hidden = temp[0] * x ; xh = fp16(x)
__global__ __launch_bounds__(256) void init_kernel(const float4* __restrict__ x,
                                                   float4* __restrict__ hidden,
                                                   __half* __restrict__ xh,
                                                   const float* __restrict__ temp, int n4) {
    int i = blockIdx.x * 256 + threadIdx.x;
    if (i >= n4) return;
    float t = temp[0];
    float4 v = x[i];
    hidden[i] = make_float4(v.x * t, v.y * t, v.z * t, v.w * t);
    union { __half2 hh[2]; float2 f2; } u;
    u.hh[0] = __floats2half2_rn(v.x, v.y);
    u.hh[1] = __floats2half2_rn(v.z, v.w);
    *(float2*)(xh + (size_t)i * 4) = u.f2;
}

// ---------------- XCD-partitioned padded-bucket build ----------------
// nt loads: keep the 3 edge streams out of L2 so edge_buf lines stay resident
// (measured WRITE_SIZE 40MB vs ~7MB ideal = partial-line thrash).
// src/w preloaded vectorized + packed unconditionally: only atomic->store is
// a dependent chain now.
__global__ __launch_bounds__(256) void bucket_kernel(const int* __restrict__ src,
                                                     const int* __restrict__ dst,
                                                     const float* __restrict__ w,
                                                     int* __restrict__ cnt,
                                                     int* __restrict__ edge_buf) {
    int g     = blockIdx.x & 7;
    int chunk = blockIdx.x >> 3;
    int base  = (chunk * 256 + threadIdx.x) * EPB;
    #pragma unroll
    for (int j = 0; j < EPB; j += 4) {
        int e = base + j;
        if (e >= N_EDGES) break;
        intv4 d4 = __builtin_nontemporal_load((const intv4*)(dst + e));
        intv4 s4 = __builtin_nontemporal_load((const intv4*)(src + e));
        fltv4 w4 = __builtin_nontemporal_load((const fltv4*)(w + e));
        int p0 = pack_edge(s4[0], w4[0]);
        int p1 = pack_edge(s4[1], w4[1]);
        int p2 = pack_edge(s4[2], w4[2]);
        int p3 = pack_edge(s4[3], w4[3]);
        if ((d4[0] & 7) == g) { int pos = atomicAdd(&cnt[d4[0]], 1); edge_buf[(size_t)d4[0] * SLOT + pos] = p0; }
        if ((d4[1] & 7) == g) { int pos = atomicAdd(&cnt[d4[1]], 1); edge_buf[(size_t)d4[1] * SLOT + pos] = p1; }
        if ((d4[2] & 7) == g) { int pos = atomicAdd(&cnt[d4[2]], 1); edge_buf[(size_t)d4[2] * SLOT + pos] = p2; }
        if ((d4[3] & 7) == g) { int pos = atomicAdd(&cnt[d4[3]], 1); edge_buf[(size_t)d4[3] * SLOT + pos] = p3; }
    }
}

// W[l] fp32 [K][N] -> Wt fp16 [N][K], all layers in one dispatch
__global__ __launch_bounds__(256) void wt_prep_kernel(const float* __restrict__ W,
                                                      __half* __restrict__ Wt) {
    int i = blockIdx.x * 256 + threadIdx.x;
    if (i >= LAYERS * DIM * DIM) return;
    int l   = i >> 14;
    int rem = i & 16383;
    int k = rem >> 7;
    int n = rem & 127;
    Wt[(size_t)l * DIM * DIM + n * DIM + k] = __float2half(W[(size_t)l * DIM * DIM + k * DIM + n]);
}

// Process 8 edges (slots base..base+7, meta register m) for this lane's node.
// Accumulates A = sum(w * x[src]) (NO relu here -- linear layer is applied
// after the gather via segsum(w*(xW+b)[src]) = (segsum(w*x[src]))W + (segsum w)*b).
// Also accumulates wsum = segsum(w) for the bias term.
__device__ __forceinline__ void batch8(const half8* __restrict__ h8,
                                       int m, int base, int cnt_r, int r, int c,
                                       float* accf, float& wsum) {
    half8 v[8]; float wv[8];
    #pragma unroll
    for (int u = 0; u < 8; ++u) {
        int jj = base + u;
        int p  = __shfl(m, (r << 4) | (jj & 15), 64);
        wv[u]  = (jj < cnt_r)
                   ? __half2float(__ushort_as_half((unsigned short)((unsigned)p >> 16)))
                   : 0.f;
        v[u]   = h8[(size_t)(p & 0xFFFF) * 16 + c];
    }
    #pragma unroll
    for (int u = 0; u < 8; ++u) {
        wsum += wv[u];
        #pragma unroll
        for (int t = 0; t < 8; ++t)
            accf[t] += wv[u] * (float)v[u][t];
    }
}

// Fused layer: gather A = segsum(w * xin[src]) -> 16x128 tile in LDS (fp16) ->
// MFMA A@W + win*b -> relu -> xout fp16 + hidden update. One kernel per layer
// replaces gemm+gather. W read directly from global (L2-hot, 32KB/block).
#define AP 136
__global__ __launch_bounds__(256) void layer_kernel(const half8* __restrict__ xin8,
                                                    const int* __restrict__ cnt_arr,
                                                    const int* __restrict__ edge_buf,
                                                    const __half* __restrict__ Wt,
                                                    const float* __restrict__ bl,
                                                    __half* __restrict__ xout_h,
                                                    float* __restrict__ hidden,
                                                    const float* __restrict__ temp,
                                                    int li) {
    __shared__ __half Ah[16][AP];
    __shared__ float winS[16];
    int tid  = threadIdx.x;
    int wave = tid >> 6;
    int lane = tid & 63;
    int r = lane >> 4;    // node subgroup 0..3
    int c = lane & 15;    // 16B chunk within row
    int node0  = blockIdx.x * 16 + wave * 4;
    int node_r = node0 + r;

    // all upfront, independent: 3 meta regs (slots 0-47, unguarded) + cnt4
    size_t mb = (size_t)node_r * SLOT;
    int m0 = edge_buf[mb + c];
    int m1 = edge_buf[mb + 16 + c];
    int m2 = edge_buf[mb + 32 + c];
    int4 c4 = *(const int4*)(cnt_arr + node0);

    int cnt_r = (r == 0) ? c4.x : (r == 1) ? c4.y : (r == 2) ? c4.z : c4.w;
    int maxc  = max(max(c4.x, c4.y), max(c4.z, c4.w));   // wave-uniform

    float accf[8];
    #pragma unroll
    for (int t = 0; t < 8; ++t) accf[t] = 0.f;
    float wsum = 0.f;

    batch8(xin8, m0, 0, cnt_r, r, c, accf, wsum);
    batch8(xin8, m0, 8, cnt_r, r, c, accf, wsum);
    if (maxc > 16) {
        batch8(xin8, m1, 16, cnt_r, r, c, accf, wsum);
        batch8(xin8, m1, 24, cnt_r, r, c, accf, wsum);
    }
    if (maxc > 32) {
        batch8(xin8, m2, 32, cnt_r, r, c, accf, wsum);
        batch8(xin8, m2, 40, cnt_r, r, c, accf, wsum);
    }

    // A tile (fp32 acc -> fp16) into LDS; 16 rows x 128 cols
    union { __half2 hh[4]; float4 f4; } ua;
    ua.hh[0] = __floats2half2_rn(accf[0], accf[1]);
    ua.hh[1] = __floats2half2_rn(accf[2], accf[3]);
    ua.hh[2] = __floats2half2_rn(accf[4], accf[5]);
    ua.hh[3] = __floats2half2_rn(accf[6], accf[7]);
    int lr = wave * 4 + r;
    *(float4*)&Ah[lr][c * 8] = ua.f4;
    if (c == 0) winS[lr] = wsum;
    __syncthreads();

    // MFMA tail: wave computes rows 0..15 x cols [wave*32, wave*32+32)
    int am  = lane & 15;
    int ak8 = (lane >> 4) * 8;
    float4v acc0 = (float4v)(0.f), acc1 = (float4v)(0.f);
    #pragma unroll
    for (int kk = 0; kk < 4; ++kk) {
        int k0 = kk * 32 + ak8;
        half8 a  = *(const half8*)&Ah[am][k0];
        half8 b0 = *(const half8*)(Wt + (size_t)(wave * 32 + am) * DIM + k0);
        half8 b1 = *(const half8*)(Wt + (size_t)(wave * 32 + 16 + am) * DIM + k0);
        acc0 = __builtin_amdgcn_mfma_f32_16x16x32_f16(a, b0, acc0, 0, 0, 0);
        acc1 = __builtin_amdgcn_mfma_f32_16x16x32_f16(a, b1, acc1, 0, 0, 0);
    }
    __syncthreads();

    // epilogue: + win*b, relu, back to LDS fp16 for coalesced stores
    int q  = lane >> 4;
    int cc = lane & 15;
    {
        int col = wave * 32 + cc;
        float bv = bl[col];
        #pragma unroll
        for (int j = 0; j < 4; ++j) {
            int row = q * 4 + j;
            Ah[row][col] = __float2half(fmaxf(acc0[j] + winS[row] * bv, 0.f));
        }
        col = wave * 32 + 16 + cc;
        bv = bl[col];
        #pragma unroll
        for (int j = 0; j < 4; ++j) {
            int row = q * 4 + j;
            Ah[row][col] = __float2half(fmaxf(acc1[j] + winS[row] * bv, 0.f));
        }
    }
    __syncthreads();

    // 256 threads == 16 rows x 16 chunks: full-width coalesced stores
    int row = tid >> 4;
    int ch  = (tid & 15) * 8;
    int gnode = blockIdx.x * 16 + row;
    size_t o = (size_t)gnode * DIM + ch;
    half8 hv = *(const half8*)&Ah[row][ch];
    *(float4*)(xout_h + o) = *(float4*)&hv;
    float tl = temp[li];
    float4 h0 = *(float4*)(hidden + o);
    float4 h1 = *(float4*)(hidden + o + 4);
    h0.x += tl * (float)hv[0]; h0.y += tl * (float)hv[1];
    h0.z += tl * (float)hv[2]; h0.w += tl * (float)hv[3];
    h1.x += tl * (float)hv[4]; h1.y += tl * (float)hv[5];
    h1.z += tl * (float)hv[6]; h1.w += tl * (float)hv[7];
    *(float4*)(hidden + o)     = h0;
    *(float4*)(hidden + o + 4) = h1;
}

extern "C" void kernel_launch(void* const* d_in, const int* in_sizes, int n_in,
                              void* d_out, int out_size, void* d_ws, size_t ws_size,
                              hipStream_t stream) {
    const float* x    = (const float*)d_in[0];
    const float* w    = (const float*)d_in[1];
    const int*   src  = (const int*)d_in[2];
    const int*   dst  = (const int*)d_in[3];
    const float* W    = (const float*)d_in[4];
    const float* b    = (const float*)d_in[5];
    const float* temp = (const float*)d_in[6];
    float* hidden = (float*)d_out;

    char* ws = (char*)d_ws;
    // ping-pong fp16 x buffers (layer kernel reads one, writes the other)
    __half* xhA      = (__half*)ws;                   ws += (size_t)N_NODES * DIM * sizeof(__half);
    __half* xhB      = (__half*)ws;                   ws += (size_t)N_NODES * DIM * sizeof(__half);
    __half* Wt       = (__half*)ws;                   ws += (size_t)LAYERS * DIM * DIM * sizeof(__half);
    int*    cnt      = (int*)ws;                      ws += (size_t)N_NODES * sizeof(int);
    int*    edge_buf = (int*)ws;                      ws += (size_t)(N_NODES * SLOT + 64) * sizeof(int);

    const int n4 = N_NODES * DIM / 4;

    // --- XCD-partitioned bucket build + weight prep (every call) ---
    hipMemsetAsync(cnt, 0, (size_t)N_NODES * sizeof(int), stream);
    {
        int chunks = (N_EDGES + 256 * EPB - 1) / (256 * EPB);   // 391
        bucket_kernel<<<chunks * 8, 256, 0, stream>>>(src, dst, w, cnt, edge_buf);
    }
    wt_prep_kernel<<<(LAYERS * DIM * DIM + 255) / 256, 256, 0, stream>>>(W, Wt);

    init_kernel<<<(n4 + 255) / 256, 256, 0, stream>>>((const float4*)x, (float4*)hidden, xhA, temp, n4);

    const int layer_blocks = N_NODES / 16;   // 3125, exact
    __half* bufs[2] = { xhA, xhB };
    for (int l = 0; l < LAYERS; ++l) {
        layer_kernel<<<layer_blocks, 256, 0, stream>>>(
            (const half8*)bufs[l & 1], cnt, edge_buf,
            Wt + (size_t)l * DIM * DIM, b + (size_t)l * DIM,
            bufs[(l & 1) ^ 1], hidden, temp, l + 1);
    }
}

// Round 2
// 305.022 us; speedup vs baseline: 1.0673x; 1.0145x over previous
//
#include <hip/hip_runtime.h>
#include <hip/hip_fp16.h>

#define N_NODES 50000
#define N_EDGES 800000
#define DIM 128
#define LAYERS 4
#define SLOT 48           // padded slots per node; 4B/slot -> node region = 192B = 3 lines
#define EPB 8             // edges scanned per thread in bucket

typedef __attribute__((ext_vector_type(8))) _Float16 half8;
typedef __attribute__((ext_vector_type(4))) float float4v;

// pack: src (u16) | w (fp16) << 16
__device__ __forceinline__ int pack_edge(int s, float w) {
    return (int)(((unsigned)__half_as_ushort(__float2half(w)) << 16) | (unsigned)(s & 0xFFFF));
}

// hidden = temp[0] * x ; xh = fp16(x)
__global__ __launch_bounds__(256) void init_kernel(const float4* __restrict__ x,
                                                   float4* __restrict__ hidden,
                                                   __half* __restrict__ xh,
                                                   const float* __restrict__ temp, int n4) {
    int i = blockIdx.x * 256 + threadIdx.x;
    if (i >= n4) return;
    float t = temp[0];
    float4 v = x[i];
    hidden[i] = make_float4(v.x * t, v.y * t, v.z * t, v.w * t);
    union { __half2 hh[2]; float2 f2; } u;
    u.hh[0] = __floats2half2_rn(v.x, v.y);
    u.hh[1] = __floats2half2_rn(v.z, v.w);
    *(float2*)(xh + (size_t)i * 4) = u.f2;
}

// ---------------- XCD-partitioned padded-bucket build ----------------
// round-0 form restored: plain (cached) loads. nt loads regressed (r1:
// 43->49.6us, FETCH 59.5->63.6MB) because replicas 2-8 of the x8 edge-stream
// scan were L2/L3-absorbed; nt defeated that reuse.
__global__ __launch_bounds__(256) void bucket_kernel(const int* __restrict__ src,
                                                     const int* __restrict__ dst,
                                                     const float* __restrict__ w,
                                                     int* __restrict__ cnt,
                                                     int* __restrict__ edge_buf) {
    int g     = blockIdx.x & 7;
    int chunk = blockIdx.x >> 3;
    int base  = (chunk * 256 + threadIdx.x) * EPB;
    #pragma unroll
    for (int j = 0; j < EPB; j += 4) {
        int e = base + j;
        if (e >= N_EDGES) break;
        int4 d4 = *(const int4*)(dst + e);
        if ((d4.x & 7) == g) {
            int pos = atomicAdd(&cnt[d4.x], 1);
            edge_buf[(size_t)d4.x * SLOT + pos] = pack_edge(src[e + 0], w[e + 0]);
        }
        if ((d4.y & 7) == g) {
            int pos = atomicAdd(&cnt[d4.y], 1);
            edge_buf[(size_t)d4.y * SLOT + pos] = pack_edge(src[e + 1], w[e + 1]);
        }
        if ((d4.z & 7) == g) {
            int pos = atomicAdd(&cnt[d4.z], 1);
            edge_buf[(size_t)d4.z * SLOT + pos] = pack_edge(src[e + 2], w[e + 2]);
        }
        if ((d4.w & 7) == g) {
            int pos = atomicAdd(&cnt[d4.w], 1);
            edge_buf[(size_t)d4.w * SLOT + pos] = pack_edge(src[e + 3], w[e + 3]);
        }
    }
}

// W[l] fp32 [K][N] -> Wt fp16 [N][K], all layers in one dispatch
__global__ __launch_bounds__(256) void wt_prep_kernel(const float* __restrict__ W,
                                                      __half* __restrict__ Wt) {
    int i = blockIdx.x * 256 + threadIdx.x;
    if (i >= LAYERS * DIM * DIM) return;
    int l   = i >> 14;
    int rem = i & 16383;
    int k = rem >> 7;
    int n = rem & 127;
    Wt[(size_t)l * DIM * DIM + n * DIM + k] = __float2half(W[(size_t)l * DIM * DIM + k * DIM + n]);
}

// Process 8 edges (slots base..base+7, meta register m) for this lane's node.
// Accumulates A = sum(w * x[src]) (linear layer applied AFTER the gather:
// segsum(w*(xW+b)[src]) = (segsum(w*x[src]))W + (segsum w)*b).
// Dead slots (jj >= cnt_r): load is EXEC-MASKED OFF (predicate is uniform per
// 16-lane subgroup) so no L2/L3 bandwidth is spent on poison rows. v zeroed
// to keep the dead FMA path NaN-free.
__device__ __forceinline__ void batch8(const half8* __restrict__ h8,
                                       int m, int base, int cnt_r, int r, int c,
                                       float* accf, float& wsum) {
    half8 v[8]; float wv[8];
    #pragma unroll
    for (int u = 0; u < 8; ++u) {
        int jj = base + u;
        int p  = __shfl(m, (r << 4) | (jj & 15), 64);
        bool live = (jj < cnt_r);
        wv[u] = live
                  ? __half2float(__ushort_as_half((unsigned short)((unsigned)p >> 16)))
                  : 0.f;
        half8 vv = (half8)(0.f);
        if (live) vv = h8[(size_t)(p & 0xFFFF) * 16 + c];
        v[u] = vv;
    }
    #pragma unroll
    for (int u = 0; u < 8; ++u) {
        wsum += wv[u];
        #pragma unroll
        for (int t = 0; t < 8; ++t)
            accf[t] += wv[u] * (float)v[u][t];
    }
}

// Fused layer: gather A = segsum(w * xin[src]) -> 16x128 tile in LDS (fp16) ->
// MFMA A@W + win*b -> relu -> xout fp16 + hidden update. One kernel per layer
// replaces gemm+gather. W read directly from global (L2-hot, 32KB/block).
#define AP 136
__global__ __launch_bounds__(256) void layer_kernel(const half8* __restrict__ xin8,
                                                    const int* __restrict__ cnt_arr,
                                                    const int* __restrict__ edge_buf,
                                                    const __half* __restrict__ Wt,
                                                    const float* __restrict__ bl,
                                                    __half* __restrict__ xout_h,
                                                    float* __restrict__ hidden,
                                                    const float* __restrict__ temp,
                                                    int li) {
    __shared__ __half Ah[16][AP];
    __shared__ float winS[16];
    int tid  = threadIdx.x;
    int wave = tid >> 6;
    int lane = tid & 63;
    int r = lane >> 4;    // node subgroup 0..3
    int c = lane & 15;    // 16B chunk within row
    int node0  = blockIdx.x * 16 + wave * 4;
    int node_r = node0 + r;

    // all upfront, independent: 3 meta regs (slots 0-47, unguarded) + cnt4
    size_t mb = (size_t)node_r * SLOT;
    int m0 = edge_buf[mb + c];
    int m1 = edge_buf[mb + 16 + c];
    int m2 = edge_buf[mb + 32 + c];
    int4 c4 = *(const int4*)(cnt_arr + node0);

    int cnt_r = (r == 0) ? c4.x : (r == 1) ? c4.y : (r == 2) ? c4.z : c4.w;
    int maxc  = max(max(c4.x, c4.y), max(c4.z, c4.w));   // wave-uniform

    float accf[8];
    #pragma unroll
    for (int t = 0; t < 8; ++t) accf[t] = 0.f;
    float wsum = 0.f;

    batch8(xin8, m0, 0, cnt_r, r, c, accf, wsum);
    batch8(xin8, m0, 8, cnt_r, r, c, accf, wsum);
    if (maxc > 16) {
        batch8(xin8, m1, 16, cnt_r, r, c, accf, wsum);
        batch8(xin8, m1, 24, cnt_r, r, c, accf, wsum);
    }
    if (maxc > 32) {
        batch8(xin8, m2, 32, cnt_r, r, c, accf, wsum);
        batch8(xin8, m2, 40, cnt_r, r, c, accf, wsum);
    }

    // A tile (fp32 acc -> fp16) into LDS; 16 rows x 128 cols
    union { __half2 hh[4]; float4 f4; } ua;
    ua.hh[0] = __floats2half2_rn(accf[0], accf[1]);
    ua.hh[1] = __floats2half2_rn(accf[2], accf[3]);
    ua.hh[2] = __floats2half2_rn(accf[4], accf[5]);
    ua.hh[3] = __floats2half2_rn(accf[6], accf[7]);
    int lr = wave * 4 + r;
    *(float4*)&Ah[lr][c * 8] = ua.f4;
    if (c == 0) winS[lr] = wsum;
    __syncthreads();

    // MFMA tail: wave computes rows 0..15 x cols [wave*32, wave*32+32)
    int am  = lane & 15;
    int ak8 = (lane >> 4) * 8;
    float4v acc0 = (float4v)(0.f), acc1 = (float4v)(0.f);
    #pragma unroll
    for (int kk = 0; kk < 4; ++kk) {
        int k0 = kk * 32 + ak8;
        half8 a  = *(const half8*)&Ah[am][k0];
        half8 b0 = *(const half8*)(Wt + (size_t)(wave * 32 + am) * DIM + k0);
        half8 b1 = *(const half8*)(Wt + (size_t)(wave * 32 + 16 + am) * DIM + k0);
        acc0 = __builtin_amdgcn_mfma_f32_16x16x32_f16(a, b0, acc0, 0, 0, 0);
        acc1 = __builtin_amdgcn_mfma_f32_16x16x32_f16(a, b1, acc1, 0, 0, 0);
    }
    __syncthreads();

    // epilogue: + win*b, relu, back to LDS fp16 for coalesced stores
    int q  = lane >> 4;
    int cc = lane & 15;
    {
        int col = wave * 32 + cc;
        float bv = bl[col];
        #pragma unroll
        for (int j = 0; j < 4; ++j) {
            int row = q * 4 + j;
            Ah[row][col] = __float2half(fmaxf(acc0[j] + winS[row] * bv, 0.f));
        }
        col = wave * 32 + 16 + cc;
        bv = bl[col];
        #pragma unroll
        for (int j = 0; j < 4; ++j) {
            int row = q * 4 + j;
            Ah[row][col] = __float2half(fmaxf(acc1[j] + winS[row] * bv, 0.f));
        }
    }
    __syncthreads();

    // 256 threads == 16 rows x 16 chunks: full-width coalesced stores
    int row = tid >> 4;
    int ch  = (tid & 15) * 8;
    int gnode = blockIdx.x * 16 + row;
    size_t o = (size_t)gnode * DIM + ch;
    half8 hv = *(const half8*)&Ah[row][ch];
    *(float4*)(xout_h + o) = *(float4*)&hv;
    float tl = temp[li];
    float4 h0 = *(float4*)(hidden + o);
    float4 h1 = *(float4*)(hidden + o + 4);
    h0.x += tl * (float)hv[0]; h0.y += tl * (float)hv[1];
    h0.z += tl * (float)hv[2]; h0.w += tl * (float)hv[3];
    h1.x += tl * (float)hv[4]; h1.y += tl * (float)hv[5];
    h1.z += tl * (float)hv[6]; h1.w += tl * (float)hv[7];
    *(float4*)(hidden + o)     = h0;
    *(float4*)(hidden + o + 4) = h1;
}

extern "C" void kernel_launch(void* const* d_in, const int* in_sizes, int n_in,
                              void* d_out, int out_size, void* d_ws, size_t ws_size,
                              hipStream_t stream) {
    const float* x    = (const float*)d_in[0];
    const float* w    = (const float*)d_in[1];
    const int*   src  = (const int*)d_in[2];
    const int*   dst  = (const int*)d_in[3];
    const float* W    = (const float*)d_in[4];
    const float* b    = (const float*)d_in[5];
    const float* temp = (const float*)d_in[6];
    float* hidden = (float*)d_out;

    char* ws = (char*)d_ws;
    // ping-pong fp16 x buffers (layer kernel reads one, writes the other)
    __half* xhA      = (__half*)ws;                   ws += (size_t)N_NODES * DIM * sizeof(__half);
    __half* xhB      = (__half*)ws;                   ws += (size_t)N_NODES * DIM * sizeof(__half);
    __half* Wt       = (__half*)ws;                   ws += (size_t)LAYERS * DIM * DIM * sizeof(__half);
    int*    cnt      = (int*)ws;                      ws += (size_t)N_NODES * sizeof(int);
    int*    edge_buf = (int*)ws;                      ws += (size_t)(N_NODES * SLOT + 64) * sizeof(int);

    const int n4 = N_NODES * DIM / 4;

    // --- XCD-partitioned bucket build + weight prep (every call) ---
    hipMemsetAsync(cnt, 0, (size_t)N_NODES * sizeof(int), stream);
    {
        int chunks = (N_EDGES + 256 * EPB - 1) / (256 * EPB);   // 391
        bucket_kernel<<<chunks * 8, 256, 0, stream>>>(src, dst, w, cnt, edge_buf);
    }
    wt_prep_kernel<<<(LAYERS * DIM * DIM + 255) / 256, 256, 0, stream>>>(W, Wt);

    init_kernel<<<(n4 + 255) / 256, 256, 0, stream>>>((const float4*)x, (float4*)hidden, xhA, temp, n4);

    const int layer_blocks = N_NODES / 16;   // 3125, exact
    __half* bufs[2] = { xhA, xhB };
    for (int l = 0; l < LAYERS; ++l) {
        layer_kernel<<<layer_blocks, 256, 0, stream>>>(
            (const half8*)bufs[l & 1], cnt, edge_buf,
            Wt + (size_t)l * DIM * DIM, b + (size_t)l * DIM,
            bufs[(l & 1) ^ 1], hidden, temp, l + 1);
    }
}

// Round 3
// 287.172 us; speedup vs baseline: 1.1337x; 1.0622x over previous
//
#include <hip/hip_runtime.h>
#include <hip/hip_fp16.h>

#define N_NODES 50000
#define N_EDGES 800000
#define DIM 128
#define LAYERS 4
#define SLOT 48           // padded slots per node; 4B/slot -> node region = 192B = 3 lines
#define EPB 8             // edges scanned per thread in bucket

typedef __attribute__((ext_vector_type(8))) _Float16 half8;
typedef __attribute__((ext_vector_type(4))) float float4v;

// pack: src (u16) | w (fp16) << 16
__device__ __forceinline__ int pack_edge(int s, float w) {
    return (int)(((unsigned)__half_as_ushort(__float2half(w)) << 16) | (unsigned)(s & 0xFFFF));
}

// xh = fp16(x). (hidden is NOT initialized here anymore -- the full GPR
// combine happens in the final layer's epilogue.)
__global__ __launch_bounds__(256) void init_kernel(const float4* __restrict__ x,
                                                   __half* __restrict__ xh, int n4) {
    int i = blockIdx.x * 256 + threadIdx.x;
    if (i >= n4) return;
    float4 v = x[i];
    union { __half2 hh[2]; float2 f2; } u;
    u.hh[0] = __floats2half2_rn(v.x, v.y);
    u.hh[1] = __floats2half2_rn(v.z, v.w);
    *(float2*)(xh + (size_t)i * 4) = u.f2;
}

// ---------------- XCD-partitioned padded-bucket build ----------------
// plain (cached) loads: nt loads regressed (r1: 43->49.6us) because replicas
// 2-8 of the x8 edge-stream scan were L2/L3-absorbed; nt defeated that reuse.
__global__ __launch_bounds__(256) void bucket_kernel(const int* __restrict__ src,
                                                     const int* __restrict__ dst,
                                                     const float* __restrict__ w,
                                                     int* __restrict__ cnt,
                                                     int* __restrict__ edge_buf) {
    int g     = blockIdx.x & 7;
    int chunk = blockIdx.x >> 3;
    int base  = (chunk * 256 + threadIdx.x) * EPB;
    #pragma unroll
    for (int j = 0; j < EPB; j += 4) {
        int e = base + j;
        if (e >= N_EDGES) break;
        int4 d4 = *(const int4*)(dst + e);
        if ((d4.x & 7) == g) {
            int pos = atomicAdd(&cnt[d4.x], 1);
            edge_buf[(size_t)d4.x * SLOT + pos] = pack_edge(src[e + 0], w[e + 0]);
        }
        if ((d4.y & 7) == g) {
            int pos = atomicAdd(&cnt[d4.y], 1);
            edge_buf[(size_t)d4.y * SLOT + pos] = pack_edge(src[e + 1], w[e + 1]);
        }
        if ((d4.z & 7) == g) {
            int pos = atomicAdd(&cnt[d4.z], 1);
            edge_buf[(size_t)d4.z * SLOT + pos] = pack_edge(src[e + 2], w[e + 2]);
        }
        if ((d4.w & 7) == g) {
            int pos = atomicAdd(&cnt[d4.w], 1);
            edge_buf[(size_t)d4.w * SLOT + pos] = pack_edge(src[e + 3], w[e + 3]);
        }
    }
}

// W[l] fp32 [K][N] -> Wt fp16 [N][K], all layers in one dispatch
__global__ __launch_bounds__(256) void wt_prep_kernel(const float* __restrict__ W,
                                                      __half* __restrict__ Wt) {
    int i = blockIdx.x * 256 + threadIdx.x;
    if (i >= LAYERS * DIM * DIM) return;
    int l   = i >> 14;
    int rem = i & 16383;
    int k = rem >> 7;
    int n = rem & 127;
    Wt[(size_t)l * DIM * DIM + n * DIM + k] = __float2half(W[(size_t)l * DIM * DIM + k * DIM + n]);
}

// Process 8 edges (slots base..base+7, meta register m) for this lane's node.
// Accumulates A = sum(w * x[src]) (linear layer applied AFTER the gather:
// segsum(w*(xW+b)[src]) = (segsum(w*x[src]))W + (segsum w)*b).
// Dead slots (jj >= cnt_r): load is EXEC-MASKED OFF (predicate is uniform per
// 16-lane subgroup) so no L2/L3 bandwidth is spent on poison rows.
__device__ __forceinline__ void batch8(const half8* __restrict__ h8,
                                       int m, int base, int cnt_r, int r, int c,
                                       float* accf, float& wsum) {
    half8 v[8]; float wv[8];
    #pragma unroll
    for (int u = 0; u < 8; ++u) {
        int jj = base + u;
        int p  = __shfl(m, (r << 4) | (jj & 15), 64);
        bool live = (jj < cnt_r);
        wv[u] = live
                  ? __half2float(__ushort_as_half((unsigned short)((unsigned)p >> 16)))
                  : 0.f;
        half8 vv = (half8)(0.f);
        if (live) vv = h8[(size_t)(p & 0xFFFF) * 16 + c];
        v[u] = vv;
    }
    #pragma unroll
    for (int u = 0; u < 8; ++u) {
        wsum += wv[u];
        #pragma unroll
        for (int t = 0; t < 8; ++t)
            accf[t] += wv[u] * (float)v[u][t];
    }
}

// Fused layer: gather A = segsum(w * xin[src]) -> 16x128 tile in LDS (fp16) ->
// MFMA A@W + win*b -> relu.
// FINAL=false: store relu'd layer output to xout_h (fp16). NO hidden traffic.
// FINAL=true : epilogue computes the whole GPR combine in one pass:
//   hidden = t0*x + t1*x1 + t2*x2 + t3*x3 + t4*out
//   (x fp32 original; x1,x2,x3 the fp16 layer outputs; xin8 == x3.)
#define AP 136
template <bool FINAL>
__global__ __launch_bounds__(256) void layer_kernel(const half8* __restrict__ xin8,
                                                    const int* __restrict__ cnt_arr,
                                                    const int* __restrict__ edge_buf,
                                                    const __half* __restrict__ Wt,
                                                    const float* __restrict__ bl,
                                                    __half* __restrict__ xout_h,
                                                    float* __restrict__ hidden,
                                                    const float* __restrict__ temp,
                                                    const float* __restrict__ xf,
                                                    const half8* __restrict__ x1h,
                                                    const half8* __restrict__ x2h) {
    __shared__ __half Ah[16][AP];
    __shared__ float winS[16];
    int tid  = threadIdx.x;
    int wave = tid >> 6;
    int lane = tid & 63;
    int r = lane >> 4;    // node subgroup 0..3
    int c = lane & 15;    // 16B chunk within row
    int node0  = blockIdx.x * 16 + wave * 4;
    int node_r = node0 + r;

    // all upfront, independent: 3 meta regs (slots 0-47, unguarded) + cnt4
    size_t mb = (size_t)node_r * SLOT;
    int m0 = edge_buf[mb + c];
    int m1 = edge_buf[mb + 16 + c];
    int m2 = edge_buf[mb + 32 + c];
    int4 c4 = *(const int4*)(cnt_arr + node0);

    int cnt_r = (r == 0) ? c4.x : (r == 1) ? c4.y : (r == 2) ? c4.z : c4.w;
    int maxc  = max(max(c4.x, c4.y), max(c4.z, c4.w));   // wave-uniform

    float accf[8];
    #pragma unroll
    for (int t = 0; t < 8; ++t) accf[t] = 0.f;
    float wsum = 0.f;

    batch8(xin8, m0, 0, cnt_r, r, c, accf, wsum);
    batch8(xin8, m0, 8, cnt_r, r, c, accf, wsum);
    if (maxc > 16) {
        batch8(xin8, m1, 16, cnt_r, r, c, accf, wsum);
        batch8(xin8, m1, 24, cnt_r, r, c, accf, wsum);
    }
    if (maxc > 32) {
        batch8(xin8, m2, 32, cnt_r, r, c, accf, wsum);
        batch8(xin8, m2, 40, cnt_r, r, c, accf, wsum);
    }

    // A tile (fp32 acc -> fp16) into LDS; 16 rows x 128 cols
    union { __half2 hh[4]; float4 f4; } ua;
    ua.hh[0] = __floats2half2_rn(accf[0], accf[1]);
    ua.hh[1] = __floats2half2_rn(accf[2], accf[3]);
    ua.hh[2] = __floats2half2_rn(accf[4], accf[5]);
    ua.hh[3] = __floats2half2_rn(accf[6], accf[7]);
    int lr = wave * 4 + r;
    *(float4*)&Ah[lr][c * 8] = ua.f4;
    if (c == 0) winS[lr] = wsum;
    __syncthreads();

    // MFMA tail: wave computes rows 0..15 x cols [wave*32, wave*32+32)
    int am  = lane & 15;
    int ak8 = (lane >> 4) * 8;
    float4v acc0 = (float4v)(0.f), acc1 = (float4v)(0.f);
    #pragma unroll
    for (int kk = 0; kk < 4; ++kk) {
        int k0 = kk * 32 + ak8;
        half8 a  = *(const half8*)&Ah[am][k0];
        half8 b0 = *(const half8*)(Wt + (size_t)(wave * 32 + am) * DIM + k0);
        half8 b1 = *(const half8*)(Wt + (size_t)(wave * 32 + 16 + am) * DIM + k0);
        acc0 = __builtin_amdgcn_mfma_f32_16x16x32_f16(a, b0, acc0, 0, 0, 0);
        acc1 = __builtin_amdgcn_mfma_f32_16x16x32_f16(a, b1, acc1, 0, 0, 0);
    }
    __syncthreads();

    // epilogue: + win*b, relu, back to LDS fp16 for coalesced stores
    int q  = lane >> 4;
    int cc = lane & 15;
    {
        int col = wave * 32 + cc;
        float bv = bl[col];
        #pragma unroll
        for (int j = 0; j < 4; ++j) {
            int row = q * 4 + j;
            Ah[row][col] = __float2half(fmaxf(acc0[j] + winS[row] * bv, 0.f));
        }
        col = wave * 32 + 16 + cc;
        bv = bl[col];
        #pragma unroll
        for (int j = 0; j < 4; ++j) {
            int row = q * 4 + j;
            Ah[row][col] = __float2half(fmaxf(acc1[j] + winS[row] * bv, 0.f));
        }
    }
    __syncthreads();

    // 256 threads == 16 rows x 16 chunks: full-width coalesced access
    int row = tid >> 4;
    int ch  = tid & 15;
    int gnode = blockIdx.x * 16 + row;
    size_t o = (size_t)gnode * DIM + ch * 8;
    half8 hv = *(const half8*)&Ah[row][ch * 8];

    if constexpr (!FINAL) {
        *(float4*)(xout_h + o) = *(float4*)&hv;
    } else {
        float t0 = temp[0], t1 = temp[1], t2 = temp[2], t3 = temp[3], t4 = temp[4];
        size_t ro = (size_t)gnode * 16 + ch;     // half8-granule row offset
        half8 v1 = x1h[ro];
        half8 v2 = x2h[ro];
        half8 v3 = xin8[ro];
        float4 x0a = *(const float4*)(xf + o);
        float4 x0b = *(const float4*)(xf + o + 4);
        float out[8];
        out[0] = t0 * x0a.x; out[1] = t0 * x0a.y; out[2] = t0 * x0a.z; out[3] = t0 * x0a.w;
        out[4] = t0 * x0b.x; out[5] = t0 * x0b.y; out[6] = t0 * x0b.z; out[7] = t0 * x0b.w;
        #pragma unroll
        for (int t = 0; t < 8; ++t)
            out[t] += t1 * (float)v1[t] + t2 * (float)v2[t]
                    + t3 * (float)v3[t] + t4 * (float)hv[t];
        float4 h0 = make_float4(out[0], out[1], out[2], out[3]);
        float4 h1 = make_float4(out[4], out[5], out[6], out[7]);
        *(float4*)(hidden + o)     = h0;
        *(float4*)(hidden + o + 4) = h1;
    }
}

extern "C" void kernel_launch(void* const* d_in, const int* in_sizes, int n_in,
                              void* d_out, int out_size, void* d_ws, size_t ws_size,
                              hipStream_t stream) {
    const float* x    = (const float*)d_in[0];
    const float* w    = (const float*)d_in[1];
    const int*   src  = (const int*)d_in[2];
    const int*   dst  = (const int*)d_in[3];
    const float* W    = (const float*)d_in[4];
    const float* b    = (const float*)d_in[5];
    const float* temp = (const float*)d_in[6];
    float* hidden = (float*)d_out;

    char* ws = (char*)d_ws;
    // 3 rotating fp16 x buffers: L1 A->B, L2 B->C, L3 C->A, L4 reads A
    // (x3) + B (x1) + C (x2) in its fused GPR-combine epilogue.
    __half* xhA      = (__half*)ws;                   ws += (size_t)N_NODES * DIM * sizeof(__half);
    __half* xhB      = (__half*)ws;                   ws += (size_t)N_NODES * DIM * sizeof(__half);
    __half* xhC      = (__half*)ws;                   ws += (size_t)N_NODES * DIM * sizeof(__half);
    __half* Wt       = (__half*)ws;                   ws += (size_t)LAYERS * DIM * DIM * sizeof(__half);
    int*    cnt      = (int*)ws;                      ws += (size_t)N_NODES * sizeof(int);
    int*    edge_buf = (int*)ws;                      ws += (size_t)(N_NODES * SLOT + 64) * sizeof(int);

    const int n4 = N_NODES * DIM / 4;

    // --- XCD-partitioned bucket build + weight prep (every call) ---
    hipMemsetAsync(cnt, 0, (size_t)N_NODES * sizeof(int), stream);
    {
        int chunks = (N_EDGES + 256 * EPB - 1) / (256 * EPB);   // 391
        bucket_kernel<<<chunks * 8, 256, 0, stream>>>(src, dst, w, cnt, edge_buf);
    }
    wt_prep_kernel<<<(LAYERS * DIM * DIM + 255) / 256, 256, 0, stream>>>(W, Wt);

    init_kernel<<<(n4 + 255) / 256, 256, 0, stream>>>((const float4*)x, xhA, n4);

    const int layer_blocks = N_NODES / 16;   // 3125, exact
    // L1: A -> B
    layer_kernel<false><<<layer_blocks, 256, 0, stream>>>(
        (const half8*)xhA, cnt, edge_buf, Wt + 0 * DIM * DIM, b + 0 * DIM,
        xhB, hidden, temp, x, nullptr, nullptr);
    // L2: B -> C
    layer_kernel<false><<<layer_blocks, 256, 0, stream>>>(
        (const half8*)xhB, cnt, edge_buf, Wt + 1 * DIM * DIM, b + 1 * DIM,
        xhC, hidden, temp, x, nullptr, nullptr);
    // L3: C -> A (x0h dead after L1)
    layer_kernel<false><<<layer_blocks, 256, 0, stream>>>(
        (const half8*)xhC, cnt, edge_buf, Wt + 2 * DIM * DIM, b + 2 * DIM,
        xhA, hidden, temp, x, nullptr, nullptr);
    // L4: reads A (x3); fused combine: hidden = t0*x + t1*B + t2*C + t3*A + t4*out
    layer_kernel<true><<<layer_blocks, 256, 0, stream>>>(
        (const half8*)xhA, cnt, edge_buf, Wt + 3 * DIM * DIM, b + 3 * DIM,
        nullptr, hidden, temp, x, (const half8*)xhB, (const half8*)xhC);
}